// Round 1
// baseline (25.866 us; speedup 1.0000x reference)
//
#include <hip/hip_runtime.h>

// TemporalCoding: out[b][t][f] = (spike_time(x[b][f]) == t && x[b][f] > 0) ? 1 : 0
// B=32, T=32, F=32768. Output 128 MiB f32 -> pure write-BW bound.

constexpr int T = 32;
constexpr int B = 32;
constexpr int F = 32768;
constexpr int NF4 = F / 4;   // 8192 float4 groups per row

__global__ __launch_bounds__(256)
void temporal_coding_kernel(const float* __restrict__ x, float* __restrict__ out) {
    const int gid = blockIdx.x * blockDim.x + threadIdx.x;   // one per (b, f4)
    const int b  = gid / NF4;
    const int f4 = gid - b * NF4;

    const float4 xv = reinterpret_cast<const float4*>(x)[(size_t)b * NF4 + f4];

    float v[4] = {xv.x, xv.y, xv.z, xv.w};
    int  st[4];
    bool act[4];
#pragma unroll
    for (int i = 0; i < 4; ++i) {
        // clip to [0,1] (same op order as jnp: clip, then (1-x)*31, trunc, clip)
        float xn = v[i];
        xn = xn < 0.0f ? 0.0f : xn;
        xn = xn > 1.0f ? 1.0f : xn;
        int s = (int)((1.0f - xn) * 31.0f);   // trunc toward zero, matches astype(int32) for s>=0
        s = s < 0 ? 0 : (s > 31 ? 31 : s);
        st[i]  = s;
        act[i] = xn > 0.0f;
    }

    float* outp = out + (size_t)b * (size_t)(T * F) + (size_t)f4 * 4;
#pragma unroll
    for (int t = 0; t < T; ++t) {
        float4 o;
        o.x = (act[0] && st[0] == t) ? 1.0f : 0.0f;
        o.y = (act[1] && st[1] == t) ? 1.0f : 0.0f;
        o.z = (act[2] && st[2] == t) ? 1.0f : 0.0f;
        o.w = (act[3] && st[3] == t) ? 1.0f : 0.0f;
        *reinterpret_cast<float4*>(outp + (size_t)t * F) = o;
    }
}

extern "C" void kernel_launch(void* const* d_in, const int* in_sizes, int n_in,
                              void* d_out, int out_size, void* d_ws, size_t ws_size,
                              hipStream_t stream) {
    const float* x = (const float*)d_in[0];
    float* out = (float*)d_out;

    const int total_threads = B * NF4;           // 262144
    const int block = 256;
    const int grid = total_threads / block;      // 1024
    temporal_coding_kernel<<<grid, block, 0, stream>>>(x, out);
}